// Round 1
// baseline (151.987 us; speedup 1.0000x reference)
//
#include <hip/hip_runtime.h>
#include <math.h>

#define NUM_E   100000
#define HIDDEN  64
#define BATCH   32
#define GAMMA_F 12.0f
#define EMB_RANGE (14.0f / 64.0f)
#define PI_F    3.14159265358979323846f

// Kernel A: compute re_rot/im_rot for all (b,d) pairs into workspace.
// rot[0 .. 2047]        = re_rot[b*64+d]
// rot[2048 .. 4095]     = im_rot[b*64+d]
__global__ void rotate_phase_kernel(const int* __restrict__ facts,
                                    const float* __restrict__ ent,
                                    const float* __restrict__ rel,
                                    float* __restrict__ rot) {
    int p = blockIdx.x * blockDim.x + threadIdx.x;   // 0..2047
    if (p >= BATCH * HIDDEN) return;
    int b = p >> 6;
    int d = p & 63;
    int f0 = facts[b * 3 + 0];
    int f1 = facts[b * 3 + 1];
    float hre = ent[(size_t)f0 * (2 * HIDDEN) + d];
    float him = ent[(size_t)f0 * (2 * HIDDEN) + HIDDEN + d];
    float r   = rel[(size_t)f1 * HIDDEN + d];
    float phase = r * (PI_F / EMB_RANGE);
    float s, c;
    sincosf(phase, &s, &c);
    rot[p]                  = hre * c - him * s;   // re_rot
    rot[BATCH * HIDDEN + p] = hre * s + him * c;   // im_rot
}

// Kernel B: one thread per entity; 32 batch accumulators in registers.
// Entity row (128 floats) is read exactly once per entity via float4.
// Rotation values come from LDS; all lanes of a wave read the same address
// at the same time -> broadcast, no bank conflicts.
__global__ __launch_bounds__(256) void rotate_dist_kernel(
        const float* __restrict__ ent,
        const float* __restrict__ rot,
        float* __restrict__ out) {
    __shared__ float s_rot[2 * BATCH * HIDDEN];   // 16 KB
    for (int i = threadIdx.x; i < 2 * BATCH * HIDDEN; i += 256)
        s_rot[i] = rot[i];
    __syncthreads();

    int e = blockIdx.x * 256 + threadIdx.x;
    if (e >= NUM_E) return;

    const float4* ent4 = (const float4*)(ent + (size_t)e * (2 * HIDDEN));

    float acc[BATCH];
#pragma unroll
    for (int b = 0; b < BATCH; ++b) acc[b] = 0.0f;

#pragma unroll 2
    for (int dc = 0; dc < HIDDEN / 4; ++dc) {     // 16 chunks of 4 dims
        float4 tr = ent4[dc];                     // re_tail[4dc..4dc+3]
        float4 ti = ent4[HIDDEN / 4 + dc];        // im_tail[4dc..4dc+3]
#pragma unroll
        for (int b = 0; b < BATCH; ++b) {
            float4 rr = *(const float4*)&s_rot[b * HIDDEN + dc * 4];
            float4 ri = *(const float4*)&s_rot[BATCH * HIDDEN + b * HIDDEN + dc * 4];
            float dx, dy;
            dx = rr.x - tr.x; dy = ri.x - ti.x;
            acc[b] += __builtin_amdgcn_sqrtf(dx * dx + dy * dy);
            dx = rr.y - tr.y; dy = ri.y - ti.y;
            acc[b] += __builtin_amdgcn_sqrtf(dx * dx + dy * dy);
            dx = rr.z - tr.z; dy = ri.z - ti.z;
            acc[b] += __builtin_amdgcn_sqrtf(dx * dx + dy * dy);
            dx = rr.w - tr.w; dy = ri.w - ti.w;
            acc[b] += __builtin_amdgcn_sqrtf(dx * dx + dy * dy);
        }
    }

#pragma unroll
    for (int b = 0; b < BATCH; ++b)
        out[(size_t)b * NUM_E + e] = GAMMA_F - acc[b];
}

extern "C" void kernel_launch(void* const* d_in, const int* in_sizes, int n_in,
                              void* d_out, int out_size, void* d_ws, size_t ws_size,
                              hipStream_t stream) {
    const int*   facts = (const int*)d_in[0];
    const float* ent   = (const float*)d_in[1];
    const float* rel   = (const float*)d_in[2];
    float*       out   = (float*)d_out;
    float*       rot   = (float*)d_ws;            // 4096 floats = 16 KB

    rotate_phase_kernel<<<dim3((BATCH * HIDDEN + 255) / 256), dim3(256), 0, stream>>>(
        facts, ent, rel, rot);

    rotate_dist_kernel<<<dim3((NUM_E + 255) / 256), dim3(256), 0, stream>>>(
        ent, rot, out);
}

// Round 2
// 135.756 us; speedup vs baseline: 1.1196x; 1.1196x over previous
//
#include <hip/hip_runtime.h>
#include <math.h>

#define NUM_E   100000
#define HIDDEN  64
#define BATCH   32
#define GAMMA_F 12.0f
#define EMB_RANGE_F 0.21875f                       // (12+2)/64
#define INV_TWO_EMB (1.0f / (2.0f * EMB_RANGE_F))  // rev = r * this = phase/(2pi)

// Kernel A: re_rot/im_rot for all (b,d) into workspace.
// rot[0..2047] = re_rot[b*64+d], rot[2048..4095] = im_rot[b*64+d]
// v_sin_f32/v_cos_f32 take REVOLUTIONS: sin(phase) = v_sin(phase/2pi).
__global__ void rotate_phase_kernel(const int* __restrict__ facts,
                                    const float* __restrict__ ent,
                                    const float* __restrict__ rel,
                                    float* __restrict__ rot) {
    int p = blockIdx.x * blockDim.x + threadIdx.x;   // 0..2047
    if (p >= BATCH * HIDDEN) return;
    int b = p >> 6;
    int d = p & 63;
    int f0 = facts[b * 3 + 0];
    int f1 = facts[b * 3 + 1];
    float hre = ent[(size_t)f0 * 128 + d];
    float him = ent[(size_t)f0 * 128 + 64 + d];
    float r   = rel[(size_t)f1 * 64 + d];
    float rev = r * INV_TWO_EMB;                 // phase/(2pi), in [-0.5, 0.5]
    float s = __builtin_amdgcn_sinf(rev);        // sin(2pi*rev) = sin(phase)
    float c = __builtin_amdgcn_cosf(rev);
    rot[p]                  = hre * c - him * s;
    rot[BATCH * HIDDEN + p] = hre * s + him * c;
}

// Kernel B: thread = (entity, dim-quarter). 400k threads -> ~24 waves/CU
// (vs 6 before: the R1 kernel was occupancy-starved at 13.5%).
// Each thread: 16 dims x 32 batches. Entity row still read exactly once
// from HBM across the whole grid. Quad butterfly (shfl_xor 1,2) combines
// the four dim-groups; lane g of each quad stores batches [8g, 8g+8).
__global__ __launch_bounds__(256) void rotate_dist_kernel(
        const float* __restrict__ ent,
        const float* __restrict__ rot,
        float* __restrict__ out) {
    __shared__ float s_rot[2 * BATCH * HIDDEN];   // 16 KB
    {
        float4* s4 = (float4*)s_rot;
        const float4* r4 = (const float4*)rot;
        for (int i = threadIdx.x; i < (2 * BATCH * HIDDEN) / 4; i += 256)
            s4[i] = r4[i];
    }
    __syncthreads();

    const int g = threadIdx.x & 3;                       // dim-chunk group
    const int e = blockIdx.x * 64 + (threadIdx.x >> 2);  // entity (same across quad)
    const int e_c = (e < NUM_E) ? e : (NUM_E - 1);       // clamp loads, guard stores

    const float4* ent4 = (const float4*)(ent + (size_t)e_c * 128);

    float acc[BATCH];
#pragma unroll
    for (int b = 0; b < BATCH; ++b) acc[b] = 0.0f;

    // This thread handles dim-chunks dc = g + 4*j, j = 0..3 (16 dims).
    // j kept as a real loop (not unrolled) to cap VGPR pressure ~70
    // so we sustain >=6 waves/SIMD.
#pragma unroll 1
    for (int j = 0; j < 4; ++j) {
        const int dc = g + 4 * j;
        float4 tr = ent4[dc];            // re_tail chunk
        float4 ti = ent4[16 + dc];       // im_tail chunk
        const float4* rr4 = (const float4*)&s_rot[dc * 4];
        const float4* ri4 = (const float4*)&s_rot[BATCH * HIDDEN + dc * 4];
#pragma unroll
        for (int b = 0; b < BATCH; ++b) {
            float4 rr = rr4[b * (HIDDEN / 4)];   // quad-broadcast, disjoint banks
            float4 ri = ri4[b * (HIDDEN / 4)];
            float dx, dy;
            dx = rr.x - tr.x; dy = ri.x - ti.x;
            acc[b] += __builtin_amdgcn_sqrtf(dx * dx + dy * dy);
            dx = rr.y - tr.y; dy = ri.y - ti.y;
            acc[b] += __builtin_amdgcn_sqrtf(dx * dx + dy * dy);
            dx = rr.z - tr.z; dy = ri.z - ti.z;
            acc[b] += __builtin_amdgcn_sqrtf(dx * dx + dy * dy);
            dx = rr.w - tr.w; dy = ri.w - ti.w;
            acc[b] += __builtin_amdgcn_sqrtf(dx * dx + dy * dy);
        }
    }

    // Butterfly across the quad: after 2 rounds all 4 lanes hold full sums.
#pragma unroll
    for (int b = 0; b < BATCH; ++b) {
        acc[b] += __shfl_xor(acc[b], 1, 64);
        acc[b] += __shfl_xor(acc[b], 2, 64);
    }

    if (e < NUM_E) {
#pragma unroll
        for (int b = 0; b < BATCH; ++b) {
            if ((b >> 3) == g)   // lane g stores batches 8g..8g+7 (16-float segments)
                out[(size_t)b * NUM_E + e] = GAMMA_F - acc[b];
        }
    }
}

extern "C" void kernel_launch(void* const* d_in, const int* in_sizes, int n_in,
                              void* d_out, int out_size, void* d_ws, size_t ws_size,
                              hipStream_t stream) {
    const int*   facts = (const int*)d_in[0];
    const float* ent   = (const float*)d_in[1];
    const float* rel   = (const float*)d_in[2];
    float*       out   = (float*)d_out;
    float*       rot   = (float*)d_ws;            // 4096 floats = 16 KB

    rotate_phase_kernel<<<dim3((BATCH * HIDDEN + 255) / 256), dim3(256), 0, stream>>>(
        facts, ent, rel, rot);

    // 64 entities per block x 4 dim-groups = 256 threads
    rotate_dist_kernel<<<dim3((NUM_E + 63) / 64), dim3(256), 0, stream>>>(
        ent, rot, out);
}